// Round 2
// baseline (979.876 us; speedup 1.0000x reference)
//
#include <hip/hip_runtime.h>

// GCN 2-layer: N=50000 nodes, E=800000 edges, F=128 feats, C=32 classes.
// Pipeline: deg -> dinv -> GEMM1(+d_out scale) -> SpMM1(atomics) ->
//           GEMM2(fused relu/d_in/b1, +d_out scale) -> SpMM2(atomics into out) -> final(d_in,b2)

#define F 128
#define C 32
#define PADN 50176  // 50000 padded

__global__ void deg_kernel(const int* __restrict__ src, const int* __restrict__ dst,
                           float* __restrict__ deg_out, float* __restrict__ deg_in, int E) {
    int i = blockIdx.x * blockDim.x + threadIdx.x;
    if (i >= E) return;
    unsafeAtomicAdd(&deg_out[src[i]], 1.0f);
    unsafeAtomicAdd(&deg_in[dst[i]], 1.0f);
}

__global__ void dinv_kernel(float* __restrict__ deg, int n) {
    int i = blockIdx.x * blockDim.x + threadIdx.x;
    if (i >= n) return;
    float d = deg[i];
    deg[i] = (d > 0.f) ? rsqrtf(d) : 1.0f;
}

// H1[n][m] = (sum_k X[n][k] W1[k][m]) * dinv_out[n]
// block: 256 threads, 32 rows x 128 cols per block; thread = (m0=tid&15 -> cols m0*4 & 64+m0*4, rr=tid>>4 -> rows rr*2, rr*2+1)
__global__ __launch_bounds__(256) void gemm1_kernel(
    const float* __restrict__ X, const float* __restrict__ W,
    const float* __restrict__ dinv_out, float* __restrict__ H1, int N) {
    __shared__ float ws[32 * 128];   // K-tile of W1: [kk][m]
    __shared__ float xs[32 * 36];    // X tile [row][kk] padded to 36 (bank spread)
    const int tid = threadIdx.x;
    const int m0 = tid & 15;
    const int rr = tid >> 4;
    const int rbase = blockIdx.x * 32;

    float4 a00 = {0,0,0,0}, a01 = {0,0,0,0}, a10 = {0,0,0,0}, a11 = {0,0,0,0};

    for (int kt = 0; kt < 4; ++kt) {
        const float4* W4 = (const float4*)(W + kt * 32 * 128);
        float4* ws4 = (float4*)ws;
#pragma unroll
        for (int j = 0; j < 4; ++j) ws4[tid + j * 256] = W4[tid + j * 256];
        {
            int r = tid >> 3, k4 = tid & 7;
            int row = rbase + r;
            float4 v = make_float4(0.f, 0.f, 0.f, 0.f);
            if (row < N) v = *(const float4*)(X + (size_t)row * F + kt * 32 + k4 * 4);
            int base = r * 36 + k4 * 4;
            xs[base] = v.x; xs[base + 1] = v.y; xs[base + 2] = v.z; xs[base + 3] = v.w;
        }
        __syncthreads();
#pragma unroll
        for (int kk = 0; kk < 32; ++kk) {
            float xa = xs[(rr * 2) * 36 + kk];
            float xb = xs[(rr * 2 + 1) * 36 + kk];
            float4 wA = *(const float4*)(ws + kk * 128 + m0 * 4);
            float4 wB = *(const float4*)(ws + kk * 128 + 64 + m0 * 4);
            a00.x += xa * wA.x; a00.y += xa * wA.y; a00.z += xa * wA.z; a00.w += xa * wA.w;
            a01.x += xa * wB.x; a01.y += xa * wB.y; a01.z += xa * wB.z; a01.w += xa * wB.w;
            a10.x += xb * wA.x; a10.y += xb * wA.y; a10.z += xb * wA.z; a10.w += xb * wA.w;
            a11.x += xb * wB.x; a11.y += xb * wB.y; a11.z += xb * wB.z; a11.w += xb * wB.w;
        }
        __syncthreads();
    }
    int row0 = rbase + rr * 2;
    int row1 = row0 + 1;
    if (row0 < N) {
        float s = dinv_out[row0];
        float4 o0 = {a00.x * s, a00.y * s, a00.z * s, a00.w * s};
        float4 o1 = {a01.x * s, a01.y * s, a01.z * s, a01.w * s};
        *(float4*)(H1 + (size_t)row0 * F + m0 * 4) = o0;
        *(float4*)(H1 + (size_t)row0 * F + 64 + m0 * 4) = o1;
    }
    if (row1 < N) {
        float s = dinv_out[row1];
        float4 o0 = {a10.x * s, a10.y * s, a10.z * s, a10.w * s};
        float4 o1 = {a11.x * s, a11.y * s, a11.z * s, a11.w * s};
        *(float4*)(H1 + (size_t)row1 * F + m0 * 4) = o0;
        *(float4*)(H1 + (size_t)row1 * F + 64 + m0 * 4) = o1;
    }
}

// AGG1[dst] += H1[src], one wave per edge, lane handles 2 consecutive floats
__global__ void spmm1_kernel(const float* __restrict__ H1, const int* __restrict__ src,
                             const int* __restrict__ dst, float* __restrict__ AGG1, int E) {
    int gid = blockIdx.x * blockDim.x + threadIdx.x;
    int e = gid >> 6;
    int l = gid & 63;
    if (e >= E) return;
    int s = src[e], d = dst[e];
    float2 v = *(const float2*)(H1 + (size_t)s * F + l * 2);
    unsafeAtomicAdd(&AGG1[(size_t)d * F + l * 2], v.x);
    unsafeAtomicAdd(&AGG1[(size_t)d * F + l * 2 + 1], v.y);
}

// H2[n][m] = (sum_k relu(AGG1[n][k]*dinv_in[n] + b1[k]) * W2[k][m]) * dinv_out[n]
// block: 256 threads, 64 rows; thread = (m0=tid&7 -> cols m0*4, rr=tid>>3 -> rows rr*2, rr*2+1)
__global__ __launch_bounds__(256) void gemm2_kernel(
    const float* __restrict__ AGG1, const float* __restrict__ b1,
    const float* __restrict__ dinv_in, const float* __restrict__ W2,
    const float* __restrict__ dinv_out, float* __restrict__ H2, int N) {
    __shared__ float ws[F * C];       // 16 KB: W2 [k][m]
    __shared__ float xs[64 * 132];    // 33.8 KB: h tile [row][k] padded
    const int tid = threadIdx.x;
    const int rbase = blockIdx.x * 64;
    {
        float4* ws4 = (float4*)ws;
        const float4* W4 = (const float4*)W2;
#pragma unroll
        for (int j = 0; j < 4; ++j) ws4[tid + j * 256] = W4[tid + j * 256];
    }
#pragma unroll
    for (int j = 0; j < 8; ++j) {
        int i4 = tid + j * 256;
        int r = i4 >> 5, k4 = i4 & 31;
        int row = rbase + r;
        float4 v = make_float4(0.f, 0.f, 0.f, 0.f);
        float di = 0.f;
        if (row < N) {
            v = *(const float4*)(AGG1 + (size_t)row * F + k4 * 4);
            di = dinv_in[row];
        }
        float4 bb = *(const float4*)(b1 + k4 * 4);
        int base = r * 132 + k4 * 4;
        xs[base]     = fmaxf(fmaf(v.x, di, bb.x), 0.f);
        xs[base + 1] = fmaxf(fmaf(v.y, di, bb.y), 0.f);
        xs[base + 2] = fmaxf(fmaf(v.z, di, bb.z), 0.f);
        xs[base + 3] = fmaxf(fmaf(v.w, di, bb.w), 0.f);
    }
    __syncthreads();
    const int m0 = tid & 7;
    const int rr = tid >> 3;
    float4 a0 = {0,0,0,0}, a1 = {0,0,0,0};
#pragma unroll 8
    for (int k = 0; k < F; ++k) {
        float4 w = *(const float4*)(ws + k * C + m0 * 4);
        float xa = xs[(rr * 2) * 132 + k];
        float xb = xs[(rr * 2 + 1) * 132 + k];
        a0.x += xa * w.x; a0.y += xa * w.y; a0.z += xa * w.z; a0.w += xa * w.w;
        a1.x += xb * w.x; a1.y += xb * w.y; a1.z += xb * w.z; a1.w += xb * w.w;
    }
    int row0 = rbase + rr * 2;
    int row1 = row0 + 1;
    if (row0 < N) {
        float s = dinv_out[row0];
        float4 o = {a0.x * s, a0.y * s, a0.z * s, a0.w * s};
        *(float4*)(H2 + (size_t)row0 * C + m0 * 4) = o;
    }
    if (row1 < N) {
        float s = dinv_out[row1];
        float4 o = {a1.x * s, a1.y * s, a1.z * s, a1.w * s};
        *(float4*)(H2 + (size_t)row1 * C + m0 * 4) = o;
    }
}

// out[dst] += H2[src], half-wave (32 lanes) per edge
__global__ void spmm2_kernel(const float* __restrict__ H2, const int* __restrict__ src,
                             const int* __restrict__ dst, float* __restrict__ out, int E) {
    int gid = blockIdx.x * blockDim.x + threadIdx.x;
    int e = gid >> 5;
    int f = gid & 31;
    if (e >= E) return;
    int s = src[e], d = dst[e];
    float v = H2[(size_t)s * C + f];
    unsafeAtomicAdd(&out[(size_t)d * C + f], v);
}

__global__ void final_kernel(float* __restrict__ out, const float* __restrict__ dinv_in,
                             const float* __restrict__ b2, int total) {
    int i = blockIdx.x * blockDim.x + threadIdx.x;
    if (i >= total) return;
    int row = i >> 5;  // / C
    int c = i & 31;
    out[i] = fmaf(out[i], dinv_in[row], b2[c]);
}

extern "C" void kernel_launch(void* const* d_in, const int* in_sizes, int n_in,
                              void* d_out, int out_size, void* d_ws, size_t ws_size,
                              hipStream_t stream) {
    const float* X  = (const float*)d_in[0];
    // d_in[1] = edge_encodings: unused by the reference
    const float* W1 = (const float*)d_in[2];
    const float* b1 = (const float*)d_in[3];
    const float* W2 = (const float*)d_in[4];
    const float* b2 = (const float*)d_in[5];
    const int*   ei = (const int*)d_in[6];

    const int N = in_sizes[0] / F;   // 50000
    const int E = in_sizes[6] / 2;   // 800000
    const int* src = ei;
    const int* dst = ei + E;

    float* ws      = (float*)d_ws;
    float* deg_out = ws;                       // PADN floats (becomes dinv_out)
    float* deg_in  = ws + PADN;                // PADN floats (becomes dinv_in)
    float* H1      = ws + 2 * PADN;            // N*F
    float* AGG1    = H1 + (size_t)N * F;       // N*F
    float* H2      = AGG1 + (size_t)N * F;     // N*C
    float* outp    = (float*)d_out;            // N*C, accumulated into

    hipMemsetAsync(deg_out, 0, (size_t)2 * PADN * sizeof(float), stream);
    hipMemsetAsync(AGG1, 0, (size_t)N * F * sizeof(float), stream);
    hipMemsetAsync(d_out, 0, (size_t)N * C * sizeof(float), stream);

    deg_kernel<<<(E + 255) / 256, 256, 0, stream>>>(src, dst, deg_out, deg_in, E);
    dinv_kernel<<<(2 * PADN + 255) / 256, 256, 0, stream>>>(deg_out, 2 * PADN);
    gemm1_kernel<<<(N + 31) / 32, 256, 0, stream>>>(X, W1, deg_out, H1, N);
    {
        long long tot = (long long)E * 64;
        spmm1_kernel<<<(int)((tot + 255) / 256), 256, 0, stream>>>(H1, src, dst, AGG1, E);
    }
    gemm2_kernel<<<(N + 63) / 64, 256, 0, stream>>>(AGG1, b1, deg_in, W2, deg_out, H2, N);
    {
        long long tot = (long long)E * 32;
        spmm2_kernel<<<(int)((tot + 255) / 256), 256, 0, stream>>>(H2, src, dst, outp, E);
    }
    final_kernel<<<((N * C) + 255) / 256, 256, 0, stream>>>(outp, deg_in, b2, N * C);
}

// Round 4
// 351.750 us; speedup vs baseline: 2.7857x; 2.7857x over previous
//
#include <hip/hip_runtime.h>

// GCN 2-layer, CSR-based aggregation, NO cross-lane ops (shfl removed vs r3).
// N=50000 nodes, E=800000 edges, F=128, C=32.
// Pipeline: cnt -> dinv -> scan(row_ptr) -> fill(eidx) ->
//           GEMM1(+d_out) -> SpMM1(gather) -> GEMM2(relu/d_in/b1, +d_out) ->
//           SpMM2(gather, fused *d_in+b2) -> out

#define F 128
#define C 32
#define PADN 50176       // 50000 padded to 49*1024
#define SCAN_BLOCKS 49   // PADN / 1024

__global__ void deg_cnt_kernel(const int* __restrict__ src, const int* __restrict__ dst,
                               int* __restrict__ cnt_out, int* __restrict__ cnt_in, int E) {
    int i = blockIdx.x * blockDim.x + threadIdx.x;
    if (i >= E) return;
    atomicAdd(&cnt_out[src[i]], 1);
    atomicAdd(&cnt_in[dst[i]], 1);
}

__global__ void dinv_kernel(const int* __restrict__ cnt_out, const int* __restrict__ cnt_in,
                            float* __restrict__ dinv_out, float* __restrict__ dinv_in, int n) {
    int i = blockIdx.x * blockDim.x + threadIdx.x;
    if (i >= n) return;
    int co = cnt_out[i], ci = cnt_in[i];
    dinv_out[i] = (co > 0) ? rsqrtf((float)co) : 1.0f;
    dinv_in[i]  = (ci > 0) ? rsqrtf((float)ci) : 1.0f;
}

// exclusive scan stage 1: each block scans 1024 ints (256 thr x 4), writes block sum
__global__ __launch_bounds__(256) void scan1_kernel(const int* __restrict__ cnt,
                                                    int* __restrict__ part, int* __restrict__ bsum) {
    __shared__ int sdata[256];
    const int tid = threadIdx.x;
    const int base = blockIdx.x * 1024 + tid * 4;
    int4 c = *(const int4*)(cnt + base);
    int s = c.x + c.y + c.z + c.w;
    sdata[tid] = s;
    __syncthreads();
    for (int off = 1; off < 256; off <<= 1) {
        int v = 0;
        if (tid >= off) v = sdata[tid - off];
        __syncthreads();
        if (tid >= off) sdata[tid] += v;
        __syncthreads();
    }
    int excl = sdata[tid] - s;
    part[base]     = excl;
    part[base + 1] = excl + c.x;
    part[base + 2] = excl + c.x + c.y;
    part[base + 3] = excl + c.x + c.y + c.z;
    if (tid == 255) bsum[blockIdx.x] = sdata[255];
}

// stage 2: exclusive scan of block sums (nb <= 256), in place
__global__ __launch_bounds__(256) void scan2_kernel(int* __restrict__ bsum, int nb) {
    __shared__ int sdata[256];
    const int tid = threadIdx.x;
    int v = (tid < nb) ? bsum[tid] : 0;
    sdata[tid] = v;
    __syncthreads();
    for (int off = 1; off < 256; off <<= 1) {
        int t = 0;
        if (tid >= off) t = sdata[tid - off];
        __syncthreads();
        if (tid >= off) sdata[tid] += t;
        __syncthreads();
    }
    if (tid < nb) bsum[tid] = sdata[tid] - v;
}

// stage 3: add block offsets; duplicate into cursor for the fill pass
__global__ void scan3_kernel(int* __restrict__ row_ptr, int* __restrict__ cursor,
                             const int* __restrict__ bsum, int n) {
    int i = blockIdx.x * blockDim.x + threadIdx.x;
    if (i >= n) return;
    int v = row_ptr[i] + bsum[i >> 10];
    row_ptr[i] = v;
    cursor[i] = v;
}

__global__ void fill_kernel(const int* __restrict__ src, const int* __restrict__ dst,
                            int* __restrict__ cursor, int* __restrict__ eidx, int E) {
    int e = blockIdx.x * blockDim.x + threadIdx.x;
    if (e >= E) return;
    int d = dst[e];
    int pos = atomicAdd(&cursor[d], 1);
    eidx[pos] = src[e];
}

// H1[n][m] = (sum_k X[n][k] W1[k][m]) * dinv_out[n]
__global__ __launch_bounds__(256) void gemm1_kernel(
    const float* __restrict__ X, const float* __restrict__ W,
    const float* __restrict__ dinv_out, float* __restrict__ H1, int N) {
    __shared__ float ws[32 * 128];
    __shared__ float xs[32 * 36];
    const int tid = threadIdx.x;
    const int m0 = tid & 15;
    const int rr = tid >> 4;
    const int rbase = blockIdx.x * 32;

    float4 a00 = {0,0,0,0}, a01 = {0,0,0,0}, a10 = {0,0,0,0}, a11 = {0,0,0,0};

    for (int kt = 0; kt < 4; ++kt) {
        const float4* W4 = (const float4*)(W + kt * 32 * 128);
        float4* ws4 = (float4*)ws;
#pragma unroll
        for (int j = 0; j < 4; ++j) ws4[tid + j * 256] = W4[tid + j * 256];
        {
            int r = tid >> 3, k4 = tid & 7;
            int row = rbase + r;
            float4 v = make_float4(0.f, 0.f, 0.f, 0.f);
            if (row < N) v = *(const float4*)(X + (size_t)row * F + kt * 32 + k4 * 4);
            int base = r * 36 + k4 * 4;
            xs[base] = v.x; xs[base + 1] = v.y; xs[base + 2] = v.z; xs[base + 3] = v.w;
        }
        __syncthreads();
#pragma unroll
        for (int kk = 0; kk < 32; ++kk) {
            float xa = xs[(rr * 2) * 36 + kk];
            float xb = xs[(rr * 2 + 1) * 36 + kk];
            float4 wA = *(const float4*)(ws + kk * 128 + m0 * 4);
            float4 wB = *(const float4*)(ws + kk * 128 + 64 + m0 * 4);
            a00.x += xa * wA.x; a00.y += xa * wA.y; a00.z += xa * wA.z; a00.w += xa * wA.w;
            a01.x += xa * wB.x; a01.y += xa * wB.y; a01.z += xa * wB.z; a01.w += xa * wB.w;
            a10.x += xb * wA.x; a10.y += xb * wA.y; a10.z += xb * wA.z; a10.w += xb * wA.w;
            a11.x += xb * wB.x; a11.y += xb * wB.y; a11.z += xb * wB.z; a11.w += xb * wB.w;
        }
        __syncthreads();
    }
    int row0 = rbase + rr * 2;
    int row1 = row0 + 1;
    if (row0 < N) {
        float s = dinv_out[row0];
        float4 o0 = {a00.x * s, a00.y * s, a00.z * s, a00.w * s};
        float4 o1 = {a01.x * s, a01.y * s, a01.z * s, a01.w * s};
        *(float4*)(H1 + (size_t)row0 * F + m0 * 4) = o0;
        *(float4*)(H1 + (size_t)row0 * F + 64 + m0 * 4) = o1;
    }
    if (row1 < N) {
        float s = dinv_out[row1];
        float4 o0 = {a10.x * s, a10.y * s, a10.z * s, a10.w * s};
        float4 o1 = {a11.x * s, a11.y * s, a11.z * s, a11.w * s};
        *(float4*)(H1 + (size_t)row1 * F + m0 * 4) = o0;
        *(float4*)(H1 + (size_t)row1 * F + 64 + m0 * 4) = o1;
    }
}

// AGG1[n][:] = sum_{e in CSR row n} H1[eidx[e]][:]
// one wave per node, lane = 2 floats; eidx loads are wave-uniform (no shfl)
__global__ __launch_bounds__(256) void spmm_csr1_kernel(
    const float* __restrict__ H1, const int* __restrict__ row_ptr,
    const int* __restrict__ cnt, const int* __restrict__ eidx,
    float* __restrict__ AGG1, int N) {
    int node = blockIdx.x * 4 + (threadIdx.x >> 6);
    if (node >= N) return;
    const int l = threadIdx.x & 63;
    const int start = row_ptr[node];
    const int deg = cnt[node];
    const float* Hb = H1 + l * 2;
    float2 a0 = {0.f,0.f}, a1 = {0.f,0.f}, a2 = {0.f,0.f}, a3 = {0.f,0.f};
    int i = 0;
    for (; i + 3 < deg; i += 4) {
        int s0 = eidx[start + i];
        int s1 = eidx[start + i + 1];
        int s2 = eidx[start + i + 2];
        int s3 = eidx[start + i + 3];
        float2 v0 = *(const float2*)(Hb + (size_t)s0 * F);
        float2 v1 = *(const float2*)(Hb + (size_t)s1 * F);
        float2 v2 = *(const float2*)(Hb + (size_t)s2 * F);
        float2 v3 = *(const float2*)(Hb + (size_t)s3 * F);
        a0.x += v0.x; a0.y += v0.y;
        a1.x += v1.x; a1.y += v1.y;
        a2.x += v2.x; a2.y += v2.y;
        a3.x += v3.x; a3.y += v3.y;
    }
    for (; i < deg; ++i) {
        int s0 = eidx[start + i];
        float2 v0 = *(const float2*)(Hb + (size_t)s0 * F);
        a0.x += v0.x; a0.y += v0.y;
    }
    float2 o = {a0.x + a1.x + a2.x + a3.x, a0.y + a1.y + a2.y + a3.y};
    *(float2*)(AGG1 + (size_t)node * F + l * 2) = o;
}

// H2[n][m] = (sum_k relu(AGG1[n][k]*dinv_in[n] + b1[k]) * W2[k][m]) * dinv_out[n]
__global__ __launch_bounds__(256) void gemm2_kernel(
    const float* __restrict__ AGG1, const float* __restrict__ b1,
    const float* __restrict__ dinv_in, const float* __restrict__ W2,
    const float* __restrict__ dinv_out, float* __restrict__ H2, int N) {
    __shared__ float ws[F * C];
    __shared__ float xs[64 * 132];
    const int tid = threadIdx.x;
    const int rbase = blockIdx.x * 64;
    {
        float4* ws4 = (float4*)ws;
        const float4* W4 = (const float4*)W2;
#pragma unroll
        for (int j = 0; j < 4; ++j) ws4[tid + j * 256] = W4[tid + j * 256];
    }
#pragma unroll
    for (int j = 0; j < 8; ++j) {
        int i4 = tid + j * 256;
        int r = i4 >> 5, k4 = i4 & 31;
        int row = rbase + r;
        float4 v = make_float4(0.f, 0.f, 0.f, 0.f);
        float di = 0.f;
        if (row < N) {
            v = *(const float4*)(AGG1 + (size_t)row * F + k4 * 4);
            di = dinv_in[row];
        }
        float4 bb = *(const float4*)(b1 + k4 * 4);
        int base = r * 132 + k4 * 4;
        xs[base]     = fmaxf(fmaf(v.x, di, bb.x), 0.f);
        xs[base + 1] = fmaxf(fmaf(v.y, di, bb.y), 0.f);
        xs[base + 2] = fmaxf(fmaf(v.z, di, bb.z), 0.f);
        xs[base + 3] = fmaxf(fmaf(v.w, di, bb.w), 0.f);
    }
    __syncthreads();
    const int m0 = tid & 7;
    const int rr = tid >> 3;
    float4 a0 = {0,0,0,0}, a1 = {0,0,0,0};
#pragma unroll 8
    for (int k = 0; k < F; ++k) {
        float4 w = *(const float4*)(ws + k * C + m0 * 4);
        float xa = xs[(rr * 2) * 132 + k];
        float xb = xs[(rr * 2 + 1) * 132 + k];
        a0.x += xa * w.x; a0.y += xa * w.y; a0.z += xa * w.z; a0.w += xa * w.w;
        a1.x += xb * w.x; a1.y += xb * w.y; a1.z += xb * w.z; a1.w += xb * w.w;
    }
    int row0 = rbase + rr * 2;
    int row1 = row0 + 1;
    if (row0 < N) {
        float s = dinv_out[row0];
        float4 o = {a0.x * s, a0.y * s, a0.z * s, a0.w * s};
        *(float4*)(H2 + (size_t)row0 * C + m0 * 4) = o;
    }
    if (row1 < N) {
        float s = dinv_out[row1];
        float4 o = {a1.x * s, a1.y * s, a1.z * s, a1.w * s};
        *(float4*)(H2 + (size_t)row1 * C + m0 * 4) = o;
    }
}

// out[n][:] = (sum_{e in row n} H2[eidx[e]][:]) * dinv_in[n] + b2
// HALF-wave (32 lanes) per node, lane = col; no cross-lane ops, no reduction
__global__ __launch_bounds__(256) void spmm_csr2_kernel(
    const float* __restrict__ H2, const int* __restrict__ row_ptr,
    const int* __restrict__ cnt, const int* __restrict__ eidx,
    const float* __restrict__ dinv_in, const float* __restrict__ b2,
    float* __restrict__ out, int N) {
    int node = blockIdx.x * 8 + (threadIdx.x >> 5);
    if (node >= N) return;
    const int col = threadIdx.x & 31;
    const int start = row_ptr[node];
    const int deg = cnt[node];
    float acc0 = 0.f, acc1 = 0.f;
    int i = 0;
    for (; i + 1 < deg; i += 2) {
        int s0 = eidx[start + i];
        int s1 = eidx[start + i + 1];
        acc0 += H2[(size_t)s0 * C + col];
        acc1 += H2[(size_t)s1 * C + col];
    }
    if (i < deg) acc0 += H2[(size_t)eidx[start + i] * C + col];
    out[(size_t)node * C + col] = fmaf(acc0 + acc1, dinv_in[node], b2[col]);
}

extern "C" void kernel_launch(void* const* d_in, const int* in_sizes, int n_in,
                              void* d_out, int out_size, void* d_ws, size_t ws_size,
                              hipStream_t stream) {
    const float* X  = (const float*)d_in[0];
    // d_in[1] = edge_encodings: unused by the reference
    const float* W1 = (const float*)d_in[2];
    const float* b1 = (const float*)d_in[3];
    const float* W2 = (const float*)d_in[4];
    const float* b2 = (const float*)d_in[5];
    const int*   ei = (const int*)d_in[6];

    const int N = in_sizes[0] / F;   // 50000
    const int E = in_sizes[6] / 2;   // 800000
    const int* src = ei;
    const int* dst = ei + E;

    float* wsf      = (float*)d_ws;
    float* dinv_out = wsf;                     // PADN
    float* dinv_in  = wsf + PADN;              // PADN
    int* cnt_out = (int*)(wsf + 2 * PADN);     // PADN
    int* cnt_in  = cnt_out + PADN;             // PADN
    int* row_ptr = cnt_in + PADN;              // PADN
    int* cursor  = row_ptr + PADN;             // PADN
    int* bsum    = cursor + PADN;              // 256
    int* eidx    = bsum + 256;                 // E
    float* H1    = (float*)(eidx + E);         // N*F (16B aligned)
    float* AGG1  = H1 + (size_t)N * F;         // N*F
    float* H2    = H1;                         // alias: H1 dead after spmm_csr1
    float* outp  = (float*)d_out;              // N*C

    hipMemsetAsync(cnt_out, 0, (size_t)2 * PADN * sizeof(int), stream);

    deg_cnt_kernel<<<(E + 255) / 256, 256, 0, stream>>>(src, dst, cnt_out, cnt_in, E);
    dinv_kernel<<<PADN / 256, 256, 0, stream>>>(cnt_out, cnt_in, dinv_out, dinv_in, PADN);
    scan1_kernel<<<SCAN_BLOCKS, 256, 0, stream>>>(cnt_in, row_ptr, bsum);
    scan2_kernel<<<1, 256, 0, stream>>>(bsum, SCAN_BLOCKS);
    scan3_kernel<<<PADN / 256, 256, 0, stream>>>(row_ptr, cursor, bsum, PADN);
    fill_kernel<<<(E + 255) / 256, 256, 0, stream>>>(src, dst, cursor, eidx, E);

    gemm1_kernel<<<(N + 31) / 32, 256, 0, stream>>>(X, W1, dinv_out, H1, N);
    spmm_csr1_kernel<<<(N + 3) / 4, 256, 0, stream>>>(H1, row_ptr, cnt_in, eidx, AGG1, N);
    gemm2_kernel<<<(N + 63) / 64, 256, 0, stream>>>(AGG1, b1, dinv_in, W2, dinv_out, H2, N);
    spmm_csr2_kernel<<<(N + 7) / 8, 256, 0, stream>>>(H2, row_ptr, cnt_in, eidx, dinv_in, b2, outp, N);
}